// Round 18
// baseline (40.276 us; speedup 1.0000x reference)
//
#include <hip/hip_runtime.h>
#include <math.h>

#define NCC 80
#define TOPKK 13
#define BB 16
#define NAA 8400
#define NMX 64
#define NROW (BB * NMX)        // 1024
#define NBA  (BB * NAA)        // 134400
#define NBK 33                 // kp x-blocks (ceil(8400/256))
#define NWRD (NBK * 4)         // 132 u64 ballot words per row
#define JZ 4                   // j-loop split across blockIdx.z
#define JPB (NMX / JZ)         // 16 gt rows per z-slice
#define SENT 0x7fffffff
#define EPSF 1e-9f
#define IOUEPS 1e-7f
#define INV_PI2 0.4052847345693511f

typedef unsigned long long u64;

__device__ __forceinline__ float ciou_pos(float gx1, float gy1, float gx2, float gy2,
                                          float gw, float gh, float gat, float inter,
                                          float px1, float py1, float px2, float py2)
{
    float w2 = px2 - px1, h2 = py2 - py1;
    float uni = gw * gh + w2 * h2 - inter + IOUEPS;
    float iou = inter / uni;
    float cw = fmaxf(gx2, px2) - fminf(gx1, px1);
    float ch = fmaxf(gy2, py2) - fminf(gy1, py1);
    float c2 = cw * cw + ch * ch + IOUEPS;
    float dx = px1 + px2 - gx1 - gx2;
    float dy = py1 + py2 - gy1 - gy2;
    float rho2 = (dx * dx + dy * dy) * 0.25f;
    float da = atanf(w2 / h2) - gat;
    float v = INV_PI2 * da * da;
    float alpha = v / (v - iou + (1.f + IOUEPS));
    return iou - (rho2 / c2 + v * alpha);
}

__device__ __forceinline__ float ciou2(float gx1, float gy1, float gx2, float gy2,
                                       float gw, float gh, float gat,
                                       float px1, float py1, float px2, float py2,
                                       float pat)
{
    float w2 = px2 - px1, h2 = py2 - py1;
    float iw = fmaxf(fminf(gx2, px2) - fmaxf(gx1, px1), 0.f);
    float ih = fmaxf(fminf(gy2, py2) - fmaxf(gy1, py1), 0.f);
    float inter = iw * ih;
    float uni = gw * gh + w2 * h2 - inter + IOUEPS;
    float iou = inter / uni;
    float cw = fmaxf(gx2, px2) - fminf(gx1, px1);
    float ch = fmaxf(gy2, py2) - fminf(gy1, py1);
    float c2 = cw * cw + ch * ch + IOUEPS;
    float dx = px1 + px2 - gx1 - gx2;
    float dy = py1 + py2 - gy1 - gy2;
    float rho2 = (dx * dx + dy * dy) * 0.25f;
    float da = pat - gat;
    float v = INV_PI2 * da * da;
    float alpha = v / (v - iou + (1.f + IOUEPS));
    return iou - (rho2 / c2 + v * alpha);
}

// KP: anchor-major positivity scan (unchanged from R17). Unconditional u64
// ballot stores; jz==0 slice zeroes cnt and pos inline.
__global__ __launch_bounds__(256) void kp_scan(
    const float* __restrict__ pd_scores,
    const float* __restrict__ pd_bboxes,
    const float* __restrict__ anc,
    const int*   __restrict__ gt_labels,
    const float* __restrict__ gt_bboxes,
    const float* __restrict__ mask_gt,
    int* __restrict__ cnt, int* __restrict__ pos,
    u64* __restrict__ bmask)
{
    const int tid = threadIdx.x;
    const int lane = tid & 63, wid = tid >> 6;
    const int b = blockIdx.y;
    const int jz = blockIdx.z;
    const int xb = blockIdx.x;
    const int a = xb * 256 + tid;
    const bool valid = a < NAA;

    __shared__ float4 glds[JPB];
    __shared__ float  mlds[JPB];
    __shared__ float  galds[JPB];
    __shared__ int    gllds[JPB];
    if (tid < JPB) {
        const int row = b * NMX + jz * JPB + tid;
        float4 gg = reinterpret_cast<const float4*>(gt_bboxes)[row];
        glds[tid] = gg;
        mlds[tid] = mask_gt[row];
        galds[tid] = atanf((gg.z - gg.x) / (gg.w - gg.y));
        gllds[tid] = gt_labels[row];
    }
    if (jz == 0 && b == 0 && xb < 8) pos[xb * 256 + tid] = 0;
    __syncthreads();

    float2 ap = valid ? reinterpret_cast<const float2*>(anc)[a]
                      : make_float2(-1e9f, -1e9f);
    float4 p  = valid ? reinterpret_cast<const float4*>(pd_bboxes)[(size_t)b * NAA + a]
                      : make_float4(0.f, 0.f, 0.f, 0.f);
    if (jz == 0 && valid) cnt[b * NAA + a] = 0;
    const float* scb = pd_scores + ((size_t)b * NAA + a) * NCC;

    for (int jj = 0; jj < JPB; ++jj) {
        float4 g = glds[jj];
        float din = fminf(fminf(ap.x - g.x, ap.y - g.y), fminf(g.z - ap.x, g.w - ap.y));
        bool cand = false;
        if (din > EPSF && mlds[jj] > 0.f) {
            float iw = fminf(g.z, p.z) - fmaxf(g.x, p.x);
            float ih = fminf(g.w, p.w) - fmaxf(g.y, p.y);
            if (iw > 0.f && ih > 0.f) {
                float c = ciou_pos(g.x, g.y, g.z, g.w, g.z - g.x, g.w - g.y,
                                   galds[jj], iw * ih, p.x, p.y, p.z, p.w);
                float o = fmaxf(c, 0.f);
                float o2 = o * o;
                float al = scb[gllds[jj]] * (o2 * o2 * o2);
                cand = al > 0.f;
            }
        }
        u64 m = __ballot(cand);
        if (lane == 0) {
            const int row = b * NMX + jz * JPB + jj;
            bmask[(size_t)row * NWRD + xb * 4 + wid] = m;   // unconditional
        }
    }
}

// KB: per-row winner selection (one wave per row). Emits winner LIST
// (wlist/wn) + plain conflict counter cnt (atomicAdd 1). Fast path n<=13:
// positives (prefix-scan slots) + ranked din-filtered fillers from {0..12}.
// Slow path n>13: recompute al, exact (val desc, idx asc) tournament.
__global__ __launch_bounds__(256) void kb_fin(
    const float* __restrict__ pd_scores,
    const float* __restrict__ pd_bboxes,
    const float* __restrict__ anc,
    const int*   __restrict__ gt_labels,
    const float* __restrict__ gt_bboxes,
    const float* __restrict__ mask_gt,
    const u64* __restrict__ bmask,
    int* __restrict__ cnt, int* __restrict__ wlist, int* __restrict__ wn)
{
    const int tid = threadIdx.x;
    const int lane = tid & 63, wid = tid >> 6;
    const int row = blockIdx.x * 4 + wid;
    if (row >= NROW || mask_gt[row] <= 0.f) return;   // wave-uniform exit
    const int b = row >> 6, j = row & 63;

    const u64* bm = bmask + (size_t)row * NWRD;
    u64 w0 = bm[lane];
    u64 w1 = bm[lane + 64];
    u64 w2 = (lane < NWRD - 128) ? bm[lane + 128] : 0ull;

    int c = __popcll(w0) + __popcll(w1) + __popcll(w2);
    int n = c;
#pragma unroll
    for (int s = 1; s < 64; s <<= 1) n += __shfl_xor(n, s, 64);

    const int cb = (int)((size_t)b * NAA);
    int* wl = wlist + row * 16;

    if (n <= TOPKK) {
        // exclusive prefix of c -> slot base
        int pre = c;
#pragma unroll
        for (int s = 1; s < 64; s <<= 1) {
            int t = __shfl_up(pre, s, 64);
            if (lane >= s) pre += t;
        }
        pre -= c;
        int slot = pre;
        {
            u64 w = w0; int base = (lane >> 2) * 256 + (lane & 3) * 64;
            while (w) { int t = __ffsll(w) - 1; w &= w - 1; int a = base + t;
                wl[slot++] = a; atomicAdd(&cnt[cb + a], 1); }
        }
        {
            int W = lane + 64;
            u64 w = w1; int base = (W >> 2) * 256 + (W & 3) * 64;
            while (w) { int t = __ffsll(w) - 1; w &= w - 1; int a = base + t;
                wl[slot++] = a; atomicAdd(&cnt[cb + a], 1); }
        }
        if (lane < NWRD - 128) {
            int W = lane + 128;
            u64 w = w2; int base = (W >> 2) * 256 + (W & 3) * 64;
            while (w) { int t = __ffsll(w) - 1; w &= w - 1; int a = base + t;
                wl[slot++] = a; atomicAdd(&cnt[cb + a], 1); }
        }
        // fillers: (13-n) smallest non-positive indices in {0..12}, din-pass
        unsigned int pmv = (lane == 0) ? (unsigned int)(w0 & 0x1fffull) : 0u;
        pmv = __shfl(pmv, 0, 64);
        bool acc = false;
        if (lane < TOPKK) {
            unsigned int bits = (~pmv) & 0x1fffu;
            if ((bits >> lane) & 1u) {
                int rank = __popc(bits & ((1u << lane) - 1u));
                if (rank < TOPKK - n) {
                    float4 g = reinterpret_cast<const float4*>(gt_bboxes)[row];
                    float2 ap = reinterpret_cast<const float2*>(anc)[lane];
                    float din = fminf(fminf(ap.x - g.x, ap.y - g.y),
                                      fminf(g.z - ap.x, g.w - ap.y));
                    acc = din > EPSF;
                }
            }
        }
        u64 am = __ballot(acc);
        if (acc) {
            int sl = n + __popcll(am & ((1ull << lane) - 1ull));
            wl[sl] = lane;
            atomicAdd(&cnt[cb + lane], 1);
        }
        if (lane == 0) wn[row] = n + __popcll(am);
        return;
    }

    // ---- slow path (rare): recompute al for positives, exact top-13 ----
    const float4 g = reinterpret_cast<const float4*>(gt_bboxes)[row];
    const float gw = g.z - g.x, gh = g.w - g.y;
    const float gat = atanf(gw / gh);
    const int gl = gt_labels[row];
    const float* sc = pd_scores + (size_t)b * NAA * NCC + gl;
    const float4* pb = reinterpret_cast<const float4*>(pd_bboxes) + (size_t)b * NAA;

    float lv[TOPKK]; int li[TOPKK];
#pragma unroll
    for (int k = 0; k < TOPKK; ++k) { lv[k] = -1.f; li[k] = SENT; }

#define INSERT(AL, A)                                                            \
    if ((AL) > lv[TOPKK - 1] || ((AL) == lv[TOPKK - 1] && (A) < li[TOPKK - 1])) { \
        lv[TOPKK - 1] = (AL); li[TOPKK - 1] = (A);                               \
        _Pragma("unroll")                                                        \
        for (int k = TOPKK - 1; k > 0; --k) {                                    \
            if (lv[k] > lv[k - 1] || (lv[k] == lv[k - 1] && li[k] < li[k - 1])) {\
                float tv = lv[k]; lv[k] = lv[k - 1]; lv[k - 1] = tv;             \
                int ti = li[k]; li[k] = li[k - 1]; li[k - 1] = ti;               \
            } else break;                                                        \
        }                                                                        \
    }

#define PROCW(WRD, WIDX)                                                         \
    {                                                                            \
        u64 w = (WRD); int base = ((WIDX) >> 2) * 256 + ((WIDX) & 3) * 64;       \
        while (w) {                                                              \
            int t = __ffsll(w) - 1; w &= w - 1;                                  \
            int a = base + t;                                                    \
            float4 p = pb[a];                                                    \
            float iw = fminf(g.z, p.z) - fmaxf(g.x, p.x);                        \
            float ih = fminf(g.w, p.w) - fmaxf(g.y, p.y);                        \
            float c2_ = ciou_pos(g.x, g.y, g.z, g.w, gw, gh, gat, iw * ih,       \
                                 p.x, p.y, p.z, p.w);                            \
            float o = fmaxf(c2_, 0.f);                                           \
            float o2 = o * o;                                                    \
            float al = sc[(size_t)a * NCC] * (o2 * o2 * o2);                     \
            INSERT(al, a);                                                       \
        }                                                                        \
    }

    PROCW(w0, lane);
    PROCW(w1, lane + 64);
    if (lane < NWRD - 128) PROCW(w2, lane + 128);
#undef PROCW
#undef INSERT

    int pp = 0;
    int myi = SENT;
    for (int rnd = 0; rnd < TOPKK; ++rnd) {
        float hv = -1.f; int hi = SENT;
#pragma unroll
        for (int k = 0; k < TOPKK; ++k) if (pp == k) { hv = lv[k]; hi = li[k]; }
        float wv = hv; int wi = hi;
#pragma unroll
        for (int s = 1; s < 64; s <<= 1) {
            float ov = __shfl_xor(wv, s, 64);
            int   oi = __shfl_xor(wi, s, 64);
            if (ov > wv || (ov == wv && oi < wi)) { wv = ov; wi = oi; }
        }
        if (lane == rnd) myi = wi;
        if (hi == wi && wi != SENT) ++pp;
    }
    if (lane < TOPKK && myi != SENT) {
        wl[lane] = myi;
        atomicAdd(&cnt[cb + myi], 1);
    }
    if (lane == 0) wn[row] = TOPKK;
}

// KR: sparse per-row resolve (one wave per row, 4 rows/block, batch-aligned).
// fg==1 -> tj = own row; fg>1 (rare) -> full-wave is-max argmax over 64 rows
// (first-argmax, = reference). Writes sparse tgt/val + pos maxima.
__global__ __launch_bounds__(256) void kr_resolve(
    const float* __restrict__ pd_scores,
    const float* __restrict__ pd_bboxes,
    const float* __restrict__ anc,
    const int*   __restrict__ gt_labels,
    const float* __restrict__ gt_bboxes,
    const float* __restrict__ mask_gt,
    const int* __restrict__ cnt,
    const int* __restrict__ wlist, const int* __restrict__ wn,
    int* __restrict__ tgt, float* __restrict__ val, int* __restrict__ pos)
{
    const int tid = threadIdx.x;
    const int lane = tid & 63, wid = tid >> 6;
    const int b = blockIdx.x >> 4;
    const int jr = (blockIdx.x & 15) * 4 + wid;   // local row 0..63
    const int row = b * NMX + jr;

    __shared__ float4 glds[NMX];
    __shared__ float  mlds[NMX];
    __shared__ float  galds[NMX];
    __shared__ int    gllds[NMX];
    if (tid < NMX) {
        float4 gg = reinterpret_cast<const float4*>(gt_bboxes)[b * NMX + tid];
        glds[tid] = gg;
        mlds[tid] = mask_gt[b * NMX + tid];
        galds[tid] = atanf((gg.z - gg.x) / (gg.w - gg.y));
        gllds[tid] = gt_labels[b * NMX + tid];
    }
    __syncthreads();

    if (mlds[jr] <= 0.f) return;   // wave-uniform
    const int nw = wn[row];
    const int cb = (int)((size_t)b * NAA);
    const float4* pb = reinterpret_cast<const float4*>(pd_bboxes) + (size_t)b * NAA;
    const float2* ap2 = reinterpret_cast<const float2*>(anc);

    int a = (lane < nw) ? wlist[row * 16 + lane] : -1;
    int fg = (a >= 0) ? cnt[cb + a] : 0;

    float al2 = 0.f, ov2 = 0.f;
    int tj = jr;
    if (a >= 0 && fg == 1) {
        // winners pass din+mask vs own row by construction
        float4 g = glds[jr];
        float4 p = pb[a];
        float pat = atanf((p.z - p.x) / (p.w - p.y));
        float c = ciou2(g.x, g.y, g.z, g.w, g.z - g.x, g.w - g.y, galds[jr],
                        p.x, p.y, p.z, p.w, pat);
        ov2 = fmaxf(c, 0.f);
        float s = pd_scores[((size_t)cb + a) * NCC + gllds[jr]];
        float o2 = ov2 * ov2;
        al2 = s * (o2 * o2 * o2);
    }

    u64 cm = __ballot(a >= 0 && fg > 1);
    while (cm) {
        int e = __ffsll(cm) - 1; cm &= cm - 1;
        int ae = __shfl(a, e, 64);
        float4 pbx = pb[ae];
        float pat = atanf((pbx.z - pbx.x) / (pbx.w - pbx.y));
        float2 apf = ap2[ae];
        float4 gr = glds[lane];
        float din = fminf(fminf(apf.x - gr.x, apf.y - gr.y),
                          fminf(gr.z - apf.x, gr.w - apf.y));
        float ov = 0.f;
        if (din > EPSF && mlds[lane] > 0.f) {
            float c = ciou2(gr.x, gr.y, gr.z, gr.w, gr.z - gr.x, gr.w - gr.y,
                            galds[lane], pbx.x, pbx.y, pbx.z, pbx.w, pat);
            ov = fmaxf(c, 0.f);
        }
        float bv = ov; int br = lane;
#pragma unroll
        for (int s = 1; s < 64; s <<= 1) {
            float o2_ = __shfl_xor(bv, s, 64);
            int   r2 = __shfl_xor(br, s, 64);
            if (o2_ > bv || (o2_ == bv && r2 < br)) { bv = o2_; br = r2; }
        }
        if (lane == e) {
            tj = br; ov2 = bv;
            float s = pd_scores[((size_t)cb + ae) * NCC + gllds[br]];
            float o2 = ov2 * ov2;
            al2 = s * (o2 * o2 * o2);
        }
    }

    if (a >= 0) {
        tgt[cb + a] = tj;
        val[cb + a] = al2;
        if (al2 > 0.f)
            atomicMax((unsigned int*)&pos[b * NMX + tj], __float_as_uint(al2));
        if (ov2 > 0.f)
            atomicMax((unsigned int*)&pos[NROW + b * NMX + tj], __float_as_uint(ov2));
    }
}

// K3: all outputs; sparse reads gated on cnt>0.
__global__ __launch_bounds__(256) void k3_out(
    const int* __restrict__ gt_labels,
    const float* __restrict__ gt_bboxes,
    const int* __restrict__ cnt,
    const int* __restrict__ tgt, const float* __restrict__ val,
    const int* __restrict__ pos,
    float* __restrict__ o_lab, float* __restrict__ o_box, float* __restrict__ o_sc,
    float* __restrict__ o_fg, float* __restrict__ o_ti)
{
    const int id0 = blockIdx.x * 256;
    const int tid = threadIdx.x;
    const int id = id0 + tid;
    const int b = id / NAA;
    const int f = cnt[id] > 0;
    const int tj = f ? tgt[id] : 0;
    int lab = gt_labels[b * NMX + tj]; lab = lab < 0 ? 0 : lab;
    float4 gb = reinterpret_cast<const float4*>(gt_bboxes)[b * NMX + tj];
    o_lab[id] = (float)lab;
    reinterpret_cast<float4*>(o_box)[id] = gb;
    o_fg[id] = f ? 1.f : 0.f;
    o_ti[id] = (float)tj;
    float v = 0.f;
    if (f) {
        float pa = __uint_as_float((unsigned int)pos[b * NMX + tj]);
        float po = __uint_as_float((unsigned int)pos[NROW + b * NMX + tj]);
        v = (val[id] * po) / (pa + EPSF);
    }
    __shared__ int   s_lab[256];
    __shared__ float s_val[256];
    s_lab[tid] = lab;
    s_val[tid] = v;
    __syncthreads();
    float4* dst = reinterpret_cast<float4*>(o_sc + (size_t)id0 * NCC);
    const int NV = 256 * NCC / 4;   // 5120 float4s per block
#pragma unroll 4
    for (int i = tid; i < NV; i += 256) {
        int aa = i / (NCC / 4);
        int c0 = (i - aa * (NCC / 4)) * 4;
        int la = s_lab[aa];
        float vv = s_val[aa];
        float4 w;
        w.x = (la == c0 + 0) ? vv : 0.f;
        w.y = (la == c0 + 1) ? vv : 0.f;
        w.z = (la == c0 + 2) ? vv : 0.f;
        w.w = (la == c0 + 3) ? vv : 0.f;
        dst[i] = w;
    }
}

extern "C" void kernel_launch(void* const* d_in, const int* in_sizes, int n_in,
                              void* d_out, int out_size, void* d_ws, size_t ws_size,
                              hipStream_t stream)
{
    const float* pd_scores = (const float*)d_in[0];
    const float* pd_bboxes = (const float*)d_in[1];
    const float* anc       = (const float*)d_in[2];
    // d_in[3] rfields: unused by the reference
    const int*   gt_labels = (const int*)d_in[4];
    const float* gt_bboxes = (const float*)d_in[5];
    const float* mask_gt   = (const float*)d_in[6];

    const size_t nba = (size_t)NBA;
    int* cnt    = (int*)d_ws;                       // NBA
    int* pos    = cnt + nba;                        // 2*NROW
    u64* bmask  = (u64*)(pos + 2 * NROW);           // NROW*NWRD u64 (8B-aligned)
    int* wlist  = (int*)(bmask + (size_t)NROW * NWRD);  // NROW*16
    int* wn     = wlist + NROW * 16;                // NROW
    int* tgt    = wn + NROW;                        // NBA
    float* val  = (float*)(tgt + nba);              // NBA

    float* out = (float*)d_out;
    float* o_lab = out;                 // (B,NA)
    float* o_box = out + nba;           // (B,NA,4)
    float* o_sc  = out + nba * 5;       // (B,NA,NC)
    float* o_fg  = out + nba * 85;      // (B,NA)
    float* o_ti  = out + nba * 86;      // (B,NA)

    kp_scan<<<dim3(NBK, BB, JZ), 256, 0, stream>>>(
        pd_scores, pd_bboxes, anc, gt_labels, gt_bboxes, mask_gt,
        cnt, pos, bmask);
    kb_fin<<<NROW / 4, 256, 0, stream>>>(pd_scores, pd_bboxes, anc, gt_labels,
                                         gt_bboxes, mask_gt, bmask,
                                         cnt, wlist, wn);
    kr_resolve<<<NROW / 4, 256, 0, stream>>>(pd_scores, pd_bboxes, anc,
                                             gt_labels, gt_bboxes, mask_gt,
                                             cnt, wlist, wn, tgt, val, pos);
    const int nblk = NBA / 256;   // 525, exact
    k3_out<<<nblk, 256, 0, stream>>>(gt_labels, gt_bboxes, cnt, tgt, val, pos,
                                     o_lab, o_box, o_sc, o_fg, o_ti);
}

// Round 20
// 37.924 us; speedup vs baseline: 1.0620x; 1.0620x over previous
//
#include <hip/hip_runtime.h>
#include <math.h>

#define NCC 80
#define TOPKK 13
#define BB 16
#define NAA 8400
#define NMX 64
#define NROW (BB * NMX)        // 1024
#define NBA  (BB * NAA)        // 134400
#define NBK 33                 // kp x-blocks (ceil(8400/256))
#define NWRD (NBK * 4)         // 132 u64 ballot words per row
#define JZ 4                   // j-loop split across blockIdx.z
#define JPB (NMX / JZ)         // 16 gt rows per z-slice
#define SENT 0x7fffffff
#define EPSF 1e-9f
#define IOUEPS 1e-7f
#define INV_PI2 0.4052847345693511f

typedef unsigned long long u64;
typedef float f4v __attribute__((ext_vector_type(4)));   // native vec for nt-store

__device__ __forceinline__ float ciou_pos(float gx1, float gy1, float gx2, float gy2,
                                          float gw, float gh, float gat, float inter,
                                          float px1, float py1, float px2, float py2)
{
    float w2 = px2 - px1, h2 = py2 - py1;
    float uni = gw * gh + w2 * h2 - inter + IOUEPS;
    float iou = inter / uni;
    float cw = fmaxf(gx2, px2) - fminf(gx1, px1);
    float ch = fmaxf(gy2, py2) - fminf(gy1, py1);
    float c2 = cw * cw + ch * ch + IOUEPS;
    float dx = px1 + px2 - gx1 - gx2;
    float dy = py1 + py2 - gy1 - gy2;
    float rho2 = (dx * dx + dy * dy) * 0.25f;
    float da = atanf(w2 / h2) - gat;
    float v = INV_PI2 * da * da;
    float alpha = v / (v - iou + (1.f + IOUEPS));
    return iou - (rho2 / c2 + v * alpha);
}

__device__ __forceinline__ float ciou2(float gx1, float gy1, float gx2, float gy2,
                                       float gw, float gh, float gat,
                                       float px1, float py1, float px2, float py2,
                                       float pat)
{
    float w2 = px2 - px1, h2 = py2 - py1;
    float iw = fmaxf(fminf(gx2, px2) - fmaxf(gx1, px1), 0.f);
    float ih = fmaxf(fminf(gy2, py2) - fmaxf(gy1, py1), 0.f);
    float inter = iw * ih;
    float uni = gw * gh + w2 * h2 - inter + IOUEPS;
    float iou = inter / uni;
    float cw = fmaxf(gx2, px2) - fminf(gx1, px1);
    float ch = fmaxf(gy2, py2) - fminf(gy1, py1);
    float c2 = cw * cw + ch * ch + IOUEPS;
    float dx = px1 + px2 - gx1 - gx2;
    float dy = py1 + py2 - gy1 - gy2;
    float rho2 = (dx * dx + dy * dy) * 0.25f;
    float da = pat - gat;
    float v = INV_PI2 * da * da;
    float alpha = v / (v - iou + (1.f + IOUEPS));
    return iou - (rho2 / c2 + v * alpha);
}

// KP: anchor-major positivity scan (unchanged from R17). Unconditional u64
// ballot stores; jz==0 slice zeroes cnt and pos inline.
__global__ __launch_bounds__(256) void kp_scan(
    const float* __restrict__ pd_scores,
    const float* __restrict__ pd_bboxes,
    const float* __restrict__ anc,
    const int*   __restrict__ gt_labels,
    const float* __restrict__ gt_bboxes,
    const float* __restrict__ mask_gt,
    int* __restrict__ cnt, int* __restrict__ pos,
    u64* __restrict__ bmask)
{
    const int tid = threadIdx.x;
    const int lane = tid & 63, wid = tid >> 6;
    const int b = blockIdx.y;
    const int jz = blockIdx.z;
    const int xb = blockIdx.x;
    const int a = xb * 256 + tid;
    const bool valid = a < NAA;

    __shared__ float4 glds[JPB];
    __shared__ float  mlds[JPB];
    __shared__ float  galds[JPB];
    __shared__ int    gllds[JPB];
    if (tid < JPB) {
        const int row = b * NMX + jz * JPB + tid;
        float4 gg = reinterpret_cast<const float4*>(gt_bboxes)[row];
        glds[tid] = gg;
        mlds[tid] = mask_gt[row];
        galds[tid] = atanf((gg.z - gg.x) / (gg.w - gg.y));
        gllds[tid] = gt_labels[row];
    }
    if (jz == 0 && b == 0 && xb < 8) pos[xb * 256 + tid] = 0;
    __syncthreads();

    float2 ap = valid ? reinterpret_cast<const float2*>(anc)[a]
                      : make_float2(-1e9f, -1e9f);
    float4 p  = valid ? reinterpret_cast<const float4*>(pd_bboxes)[(size_t)b * NAA + a]
                      : make_float4(0.f, 0.f, 0.f, 0.f);
    if (jz == 0 && valid) cnt[b * NAA + a] = 0;
    const float* scb = pd_scores + ((size_t)b * NAA + a) * NCC;

    for (int jj = 0; jj < JPB; ++jj) {
        float4 g = glds[jj];
        float din = fminf(fminf(ap.x - g.x, ap.y - g.y), fminf(g.z - ap.x, g.w - ap.y));
        bool cand = false;
        if (din > EPSF && mlds[jj] > 0.f) {
            float iw = fminf(g.z, p.z) - fmaxf(g.x, p.x);
            float ih = fminf(g.w, p.w) - fmaxf(g.y, p.y);
            if (iw > 0.f && ih > 0.f) {
                float c = ciou_pos(g.x, g.y, g.z, g.w, g.z - g.x, g.w - g.y,
                                   galds[jj], iw * ih, p.x, p.y, p.z, p.w);
                float o = fmaxf(c, 0.f);
                float o2 = o * o;
                float al = scb[gllds[jj]] * (o2 * o2 * o2);
                cand = al > 0.f;
            }
        }
        u64 m = __ballot(cand);
        if (lane == 0) {
            const int row = b * NMX + jz * JPB + jj;
            bmask[(size_t)row * NWRD + xb * 4 + wid] = m;   // unconditional
        }
    }
}

// KB: per-row finalize from ballot words, one wave per row, NO LDS, no
// block syncs. n<=13: enumerate set bits -> scatter (values never needed)
// + ranked din-filtered fillers from {0..12}. n>13 (rare): recompute al for
// each positive, depth-13 register lists, 13-round select-chain tournament,
// exact (val desc, idx asc).
__global__ __launch_bounds__(256) void kb_fin(
    const float* __restrict__ pd_scores,
    const float* __restrict__ pd_bboxes,
    const float* __restrict__ anc,
    const int*   __restrict__ gt_labels,
    const float* __restrict__ gt_bboxes,
    const float* __restrict__ mask_gt,
    const u64* __restrict__ bmask,
    int* __restrict__ cnt)
{
    const int tid = threadIdx.x;
    const int lane = tid & 63, wid = tid >> 6;
    const int row = blockIdx.x * 4 + wid;
    if (row >= NROW || mask_gt[row] <= 0.f) return;   // wave-uniform exit
    const int b = row >> 6, j = row & 63;

    const u64* bm = bmask + (size_t)row * NWRD;
    u64 w0 = bm[lane];
    u64 w1 = bm[lane + 64];
    u64 w2 = (lane < NWRD - 128) ? bm[lane + 128] : 0ull;

    int n = __popcll(w0) + __popcll(w1) + __popcll(w2);
#pragma unroll
    for (int s = 1; s < 64; s <<= 1) n += __shfl_xor(n, s, 64);

    unsigned int pmv = (lane == 0) ? (unsigned int)(w0 & 0x1fffull) : 0u;
    pmv = __shfl(pmv, 0, 64);

    const int cb = (int)((size_t)b * NAA);

    if (n <= TOPKK) {
        // ---- fast path: every positive wins; indices only ----
        {
            u64 w = w0; int base = (lane >> 2) * 256 + (lane & 3) * 64;
            while (w) { int t = __ffsll(w) - 1; w &= w - 1;
                atomicAdd(&cnt[cb + base + t], 1 + (j << 8)); }
        }
        {
            int W = lane + 64;
            u64 w = w1; int base = (W >> 2) * 256 + (W & 3) * 64;
            while (w) { int t = __ffsll(w) - 1; w &= w - 1;
                atomicAdd(&cnt[cb + base + t], 1 + (j << 8)); }
        }
        if (lane < NWRD - 128) {
            int W = lane + 128;
            u64 w = w2; int base = (W >> 2) * 256 + (W & 3) * 64;
            while (w) { int t = __ffsll(w) - 1; w &= w - 1;
                atomicAdd(&cnt[cb + base + t], 1 + (j << 8)); }
        }
        // fillers: (13-n) smallest non-positive indices, all in {0..12}
        if (lane < TOPKK) {
            unsigned int bits = (~pmv) & 0x1fffu;
            if ((bits >> lane) & 1u) {
                int rank = __popc(bits & ((1u << lane) - 1u));
                if (rank < TOPKK - n) {
                    float4 g = reinterpret_cast<const float4*>(gt_bboxes)[row];
                    float2 ap = reinterpret_cast<const float2*>(anc)[lane];
                    float din = fminf(fminf(ap.x - g.x, ap.y - g.y),
                                      fminf(g.z - ap.x, g.w - ap.y));
                    if (din > EPSF)
                        atomicAdd(&cnt[cb + lane], 1 + (j << 8));
                }
            }
        }
        return;
    }

    // ---- slow path (rare): recompute al for positives, exact top-13 ----
    const float4 g = reinterpret_cast<const float4*>(gt_bboxes)[row];
    const float gw = g.z - g.x, gh = g.w - g.y;
    const float gat = atanf(gw / gh);
    const int gl = gt_labels[row];
    const float* sc = pd_scores + (size_t)b * NAA * NCC + gl;
    const float4* pb = reinterpret_cast<const float4*>(pd_bboxes) + (size_t)b * NAA;

    float lv[TOPKK]; int li[TOPKK];
#pragma unroll
    for (int k = 0; k < TOPKK; ++k) { lv[k] = -1.f; li[k] = SENT; }

#define INSERT(AL, A)                                                            \
    if ((AL) > lv[TOPKK - 1] || ((AL) == lv[TOPKK - 1] && (A) < li[TOPKK - 1])) { \
        lv[TOPKK - 1] = (AL); li[TOPKK - 1] = (A);                               \
        _Pragma("unroll")                                                        \
        for (int k = TOPKK - 1; k > 0; --k) {                                    \
            if (lv[k] > lv[k - 1] || (lv[k] == lv[k - 1] && li[k] < li[k - 1])) {\
                float tv = lv[k]; lv[k] = lv[k - 1]; lv[k - 1] = tv;             \
                int ti = li[k]; li[k] = li[k - 1]; li[k - 1] = ti;               \
            } else break;                                                        \
        }                                                                        \
    }

#define PROCW(WRD, WIDX)                                                         \
    {                                                                            \
        u64 w = (WRD); int base = ((WIDX) >> 2) * 256 + ((WIDX) & 3) * 64;       \
        while (w) {                                                              \
            int t = __ffsll(w) - 1; w &= w - 1;                                  \
            int a = base + t;                                                    \
            float4 p = pb[a];                                                    \
            float iw = fminf(g.z, p.z) - fmaxf(g.x, p.x);                        \
            float ih = fminf(g.w, p.w) - fmaxf(g.y, p.y);                        \
            float c = ciou_pos(g.x, g.y, g.z, g.w, gw, gh, gat, iw * ih,         \
                               p.x, p.y, p.z, p.w);                              \
            float o = fmaxf(c, 0.f);                                             \
            float o2 = o * o;                                                    \
            float al = sc[(size_t)a * NCC] * (o2 * o2 * o2);                     \
            INSERT(al, a);                                                       \
        }                                                                        \
    }

    PROCW(w0, lane);
    PROCW(w1, lane + 64);
    if (lane < NWRD - 128) PROCW(w2, lane + 128);
#undef PROCW
#undef INSERT

    int pp = 0;
    int myi = SENT;
    for (int rnd = 0; rnd < TOPKK; ++rnd) {
        float hv = -1.f; int hi = SENT;
#pragma unroll
        for (int k = 0; k < TOPKK; ++k) if (pp == k) { hv = lv[k]; hi = li[k]; }
        float wv = hv; int wi = hi;
#pragma unroll
        for (int s = 1; s < 64; s <<= 1) {
            float ov = __shfl_xor(wv, s, 64);
            int   oi = __shfl_xor(wi, s, 64);
            if (ov > wv || (ov == wv && oi < wi)) { wv = ov; wi = oi; }
        }
        if (lane == rnd) myi = wi;
        if (hi == wi && wi != SENT) ++pp;
    }
    if (lane < TOPKK && myi != SENT)
        atomicAdd(&cnt[cb + myi], 1 + (j << 8));
}

// K2: per-anchor multi-gt resolution + per-row pos maxima (unchanged R17).
__global__ __launch_bounds__(256) void k2_resolve(
    const float* __restrict__ pd_scores,
    const float* __restrict__ pd_bboxes,
    const float* __restrict__ anc,
    const int*   __restrict__ gt_labels,
    const float* __restrict__ gt_bboxes,
    const float* __restrict__ mask_gt,
    const int* __restrict__ cnt,
    int* __restrict__ tgt, int* __restrict__ fgm, float* __restrict__ alv,
    int* __restrict__ pos)
{
    const int tid = threadIdx.x;
    const int b = blockIdx.y;
    const int a = blockIdx.x * 256 + tid;

    __shared__ float4 glds[NMX];
    __shared__ float  mlds[NMX];
    __shared__ float  galds[NMX];
    if (tid < NMX) {
        float4 gg = reinterpret_cast<const float4*>(gt_bboxes)[b * NMX + tid];
        glds[tid] = gg;
        mlds[tid] = mask_gt[b * NMX + tid];
        galds[tid] = atanf((gg.z - gg.x) / (gg.w - gg.y));
    }
    __syncthreads();
    if (a >= NAA) return;

    const int id = b * NAA + a;
    const int v = cnt[id];
    const int fg = v & 0xff;
    int tj = 0, f = 0;
    float al = 0.f;
    if (fg > 0) {
        f = 1;
        float2 ap = reinterpret_cast<const float2*>(anc)[a];
        float4 p = reinterpret_cast<const float4*>(pd_bboxes)[id];
        float pat = atanf((p.z - p.x) / (p.w - p.y));
        if (fg == 1) {
            tj = v >> 8;
        } else {
            float bv = -1.f; int bj = 0;
            for (int jj = 0; jj < NMX; ++jj) {
                float4 g = glds[jj];
                float din = fminf(fminf(ap.x - g.x, ap.y - g.y), fminf(g.z - ap.x, g.w - ap.y));
                float ov = 0.f;
                if (din > EPSF && mlds[jj] > 0.f) {
                    float c = ciou2(g.x, g.y, g.z, g.w, g.z - g.x, g.w - g.y, galds[jj],
                                    p.x, p.y, p.z, p.w, pat);
                    ov = fmaxf(c, 0.f);
                }
                if (ov > bv) { bv = ov; bj = jj; }   // strict > == first-argmax
            }
            tj = bj;
        }
        float4 g = glds[tj];
        float din = fminf(fminf(ap.x - g.x, ap.y - g.y), fminf(g.z - ap.x, g.w - ap.y));
        if (din > EPSF && mlds[tj] > 0.f) {
            float c = ciou2(g.x, g.y, g.z, g.w, g.z - g.x, g.w - g.y, galds[tj],
                            p.x, p.y, p.z, p.w, pat);
            float ov = fmaxf(c, 0.f);
            int gl = gt_labels[b * NMX + tj];
            float s = pd_scores[(size_t)id * NCC + gl];
            float o2 = ov * ov;
            al = s * (o2 * o2 * o2);
            if (ov > 0.f)
                atomicMax((unsigned int*)&pos[NROW + b * NMX + tj], __float_as_uint(ov));
        }
        if (al > 0.f)
            atomicMax((unsigned int*)&pos[b * NMX + tj], __float_as_uint(al));
    }
    tgt[id] = tj; fgm[id] = f; alv[id] = al;
}

// K3: all outputs; NON-TEMPORAL stores via native ext_vector f4v (outputs
// never re-read by GPU -> bypass L2 line allocation on the streaming write).
__global__ __launch_bounds__(256) void k3_out(
    const int* __restrict__ gt_labels,
    const float* __restrict__ gt_bboxes,
    const int* __restrict__ tgt, const int* __restrict__ fgm,
    const float* __restrict__ alv, const int* __restrict__ pos,
    float* __restrict__ o_lab, float* __restrict__ o_box, float* __restrict__ o_sc,
    float* __restrict__ o_fg, float* __restrict__ o_ti)
{
    const int id0 = blockIdx.x * 256;
    const int tid = threadIdx.x;
    const int id = id0 + tid;
    const int b = id / NAA;
    const int tj = tgt[id];
    const int f = fgm[id];
    int lab = gt_labels[b * NMX + tj]; lab = lab < 0 ? 0 : lab;
    float4 gb = reinterpret_cast<const float4*>(gt_bboxes)[b * NMX + tj];
    f4v gbv = { gb.x, gb.y, gb.z, gb.w };
    __builtin_nontemporal_store((float)lab, &o_lab[id]);
    __builtin_nontemporal_store(gbv, &reinterpret_cast<f4v*>(o_box)[id]);
    __builtin_nontemporal_store(f ? 1.f : 0.f, &o_fg[id]);
    __builtin_nontemporal_store((float)tj, &o_ti[id]);
    float val = 0.f;
    if (f) {
        float pa = __uint_as_float((unsigned int)pos[b * NMX + tj]);
        float po = __uint_as_float((unsigned int)pos[NROW + b * NMX + tj]);
        val = (alv[id] * po) / (pa + EPSF);
    }
    __shared__ int   s_lab[256];
    __shared__ float s_val[256];
    s_lab[tid] = lab;
    s_val[tid] = val;
    __syncthreads();
    f4v* dst = reinterpret_cast<f4v*>(o_sc + (size_t)id0 * NCC);
    const int NV = 256 * NCC / 4;   // 5120 float4s per block
#pragma unroll 4
    for (int i = tid; i < NV; i += 256) {
        int aa = i / (NCC / 4);
        int c0 = (i - aa * (NCC / 4)) * 4;
        int la = s_lab[aa];
        float vv = s_val[aa];
        f4v w;
        w.x = (la == c0 + 0) ? vv : 0.f;
        w.y = (la == c0 + 1) ? vv : 0.f;
        w.z = (la == c0 + 2) ? vv : 0.f;
        w.w = (la == c0 + 3) ? vv : 0.f;
        __builtin_nontemporal_store(w, &dst[i]);
    }
}

extern "C" void kernel_launch(void* const* d_in, const int* in_sizes, int n_in,
                              void* d_out, int out_size, void* d_ws, size_t ws_size,
                              hipStream_t stream)
{
    const float* pd_scores = (const float*)d_in[0];
    const float* pd_bboxes = (const float*)d_in[1];
    const float* anc       = (const float*)d_in[2];
    // d_in[3] rfields: unused by the reference
    const int*   gt_labels = (const int*)d_in[4];
    const float* gt_bboxes = (const float*)d_in[5];
    const float* mask_gt   = (const float*)d_in[6];

    const size_t nba = (size_t)NBA;
    int* cnt    = (int*)d_ws;                       // NBA
    int* pos    = cnt + nba;                        // 2*NROW
    u64* bmask  = (u64*)(pos + 2 * NROW);           // NROW*NWRD u64 (8B-aligned)
    int* tgt    = (int*)(bmask + (size_t)NROW * NWRD);  // NBA
    int* fgm    = tgt + nba;                        // NBA
    float* alv  = (float*)(fgm + nba);              // NBA

    float* out = (float*)d_out;
    float* o_lab = out;                 // (B,NA)
    float* o_box = out + nba;           // (B,NA,4)
    float* o_sc  = out + nba * 5;       // (B,NA,NC)
    float* o_fg  = out + nba * 85;      // (B,NA)
    float* o_ti  = out + nba * 86;      // (B,NA)

    kp_scan<<<dim3(NBK, BB, JZ), 256, 0, stream>>>(
        pd_scores, pd_bboxes, anc, gt_labels, gt_bboxes, mask_gt,
        cnt, pos, bmask);
    kb_fin<<<NROW / 4, 256, 0, stream>>>(pd_scores, pd_bboxes, anc, gt_labels,
                                         gt_bboxes, mask_gt, bmask, cnt);
    k2_resolve<<<dim3(NBK, BB), 256, 0, stream>>>(
        pd_scores, pd_bboxes, anc, gt_labels, gt_bboxes, mask_gt, cnt,
        tgt, fgm, alv, pos);
    const int nblk = NBA / 256;   // 525, exact
    k3_out<<<nblk, 256, 0, stream>>>(gt_labels, gt_bboxes, tgt, fgm, alv, pos,
                                     o_lab, o_box, o_sc, o_fg, o_ti);
}